// Round 1
// baseline (4738.025 us; speedup 1.0000x reference)
//
#include <hip/hip_runtime.h>

#define N_NODES 50000
#define N_EDGES 1600000
#define F 11
#define FEAT 27   // 2F + 1 + ED
#define NLAYERS 4
#define NGRAPH 500

__device__ __forceinline__ float siluf(float v) { return v * (1.0f / (1.0f + __expf(-v))); }
__device__ __forceinline__ float sigmf(float v) { return 1.0f / (1.0f + __expf(-v)); }

__global__ void init_copy(const float* __restrict__ h0, const float* __restrict__ pos,
                          float* __restrict__ h, float* __restrict__ x) {
    int i = blockIdx.x * blockDim.x + threadIdx.x;
    int stride = gridDim.x * blockDim.x;
    for (int k = i; k < N_NODES * F; k += stride) h[k] = h0[k];
    for (int k = i; k < N_NODES * 3; k += stride) x[k] = pos[k];
}

__global__ __launch_bounds__(256) void edge_kernel(
    const float* __restrict__ h, const float* __restrict__ x,
    const int* __restrict__ src, const int* __restrict__ dst,
    const float* __restrict__ eattr,
    const float* __restrict__ Wm1, const float* __restrict__ bm1,
    const float* __restrict__ Wm2, const float* __restrict__ bm2,
    const float* __restrict__ Wa,  const float* __restrict__ ba,
    const float* __restrict__ Wx1, const float* __restrict__ bx1,
    const float* __restrict__ Wx2, const float* __restrict__ bx2,
    const float* __restrict__ Wx3, const float* __restrict__ bx3,
    float* __restrict__ agg_h, float* __restrict__ agg_x)
{
    __shared__ float sWm1[FEAT * F], sWm2[F * F], sWx1[FEAT * F], sWx2[F * F];
    __shared__ float sbm1[F], sbm2[F], sWa[F], sbx1[F], sbx2[F], sWx3[F];
    __shared__ float sba, sbx3;
    int t = threadIdx.x;
    for (int i2 = t; i2 < FEAT * F; i2 += 256) { sWm1[i2] = Wm1[i2]; sWx1[i2] = Wx1[i2]; }
    for (int i2 = t; i2 < F * F; i2 += 256)    { sWm2[i2] = Wm2[i2]; sWx2[i2] = Wx2[i2]; }
    if (t < F) {
        sbm1[t] = bm1[t]; sbm2[t] = bm2[t]; sWa[t] = Wa[t];
        sbx1[t] = bx1[t]; sbx2[t] = bx2[t]; sWx3[t] = Wx3[t];
    }
    if (t == 0) { sba = ba[0]; sbx3 = bx3[0]; }
    __syncthreads();

    int e = blockIdx.x * 256 + t;
    if (e >= N_EDGES) return;

    int j = src[e];   // source
    int i = dst[e];   // target

    float feat[FEAT];
    #pragma unroll
    for (int f2 = 0; f2 < F; ++f2) feat[f2] = h[i * F + f2];
    #pragma unroll
    for (int f2 = 0; f2 < F; ++f2) feat[F + f2] = h[j * F + f2];

    float xi0 = x[i * 3 + 0], xi1 = x[i * 3 + 1], xi2 = x[i * 3 + 2];
    float xj0 = x[j * 3 + 0], xj1 = x[j * 3 + 1], xj2 = x[j * 3 + 2];
    float dx = xj0 - xi0, dy = xj1 - xi1, dz = xj2 - xi2;
    float d2 = dx * dx + dy * dy + dz * dz;
    feat[2 * F] = d2;
    float4 ea = reinterpret_cast<const float4*>(eattr)[e];
    feat[2 * F + 1] = ea.x; feat[2 * F + 2] = ea.y;
    feat[2 * F + 3] = ea.z; feat[2 * F + 4] = ea.w;

    // m = silu(feat @ Wm1 + bm1)
    float m[F];
    #pragma unroll
    for (int o = 0; o < F; ++o) m[o] = sbm1[o];
    #pragma unroll
    for (int fi = 0; fi < FEAT; ++fi) {
        float fv = feat[fi];
        #pragma unroll
        for (int o = 0; o < F; ++o) m[o] = fmaf(fv, sWm1[fi * F + o], m[o]);
    }
    #pragma unroll
    for (int o = 0; o < F; ++o) m[o] = siluf(m[o]);

    // m2 = silu(m @ Wm2 + bm2)
    float m2[F];
    #pragma unroll
    for (int o = 0; o < F; ++o) m2[o] = sbm2[o];
    #pragma unroll
    for (int fi = 0; fi < F; ++fi) {
        float fv = m[fi];
        #pragma unroll
        for (int o = 0; o < F; ++o) m2[o] = fmaf(fv, sWm2[fi * F + o], m2[o]);
    }
    #pragma unroll
    for (int o = 0; o < F; ++o) m2[o] = siluf(m2[o]);

    // attn = sigmoid(m2 @ Wa + ba)
    float attn = sba;
    #pragma unroll
    for (int o = 0; o < F; ++o) attn = fmaf(m2[o], sWa[o], attn);
    attn = sigmf(attn);

    // phi path
    float p1[F];
    #pragma unroll
    for (int o = 0; o < F; ++o) p1[o] = sbx1[o];
    #pragma unroll
    for (int fi = 0; fi < FEAT; ++fi) {
        float fv = feat[fi];
        #pragma unroll
        for (int o = 0; o < F; ++o) p1[o] = fmaf(fv, sWx1[fi * F + o], p1[o]);
    }
    #pragma unroll
    for (int o = 0; o < F; ++o) p1[o] = siluf(p1[o]);

    float p2[F];
    #pragma unroll
    for (int o = 0; o < F; ++o) p2[o] = sbx2[o];
    #pragma unroll
    for (int fi = 0; fi < F; ++fi) {
        float fv = p1[fi];
        #pragma unroll
        for (int o = 0; o < F; ++o) p2[o] = fmaf(fv, sWx2[fi * F + o], p2[o]);
    }
    #pragma unroll
    for (int o = 0; o < F; ++o) p2[o] = siluf(p2[o]);

    float phi = sbx3;
    #pragma unroll
    for (int o = 0; o < F; ++o) phi = fmaf(p2[o], sWx3[o], phi);

    float d = sqrtf(d2);
    float sc = phi / (d + 1.0f);

    unsafeAtomicAdd(&agg_x[i * 3 + 0], (xi0 - xj0) * sc);
    unsafeAtomicAdd(&agg_x[i * 3 + 1], (xi1 - xj1) * sc);
    unsafeAtomicAdd(&agg_x[i * 3 + 2], (xi2 - xj2) * sc);
    #pragma unroll
    for (int o = 0; o < F; ++o) unsafeAtomicAdd(&agg_h[i * F + o], attn * m2[o]);
}

__global__ __launch_bounds__(256) void node_kernel(
    float* __restrict__ h, float* __restrict__ x,
    const float* __restrict__ agg_h, const float* __restrict__ agg_x,
    const float* __restrict__ Wu1, const float* __restrict__ bu1,
    const float* __restrict__ Wu2, const float* __restrict__ bu2)
{
    __shared__ float sWu1[2 * F * F], sWu2[F * F], sbu1[F], sbu2[F];
    int t = threadIdx.x;
    for (int i2 = t; i2 < 2 * F * F; i2 += 256) sWu1[i2] = Wu1[i2];
    for (int i2 = t; i2 < F * F; i2 += 256)     sWu2[i2] = Wu2[i2];
    if (t < F) { sbu1[t] = bu1[t]; sbu2[t] = bu2[t]; }
    __syncthreads();

    int n = blockIdx.x * 256 + t;
    if (n >= N_NODES) return;

    float in[2 * F];
    #pragma unroll
    for (int f2 = 0; f2 < F; ++f2) in[f2] = h[n * F + f2];
    #pragma unroll
    for (int f2 = 0; f2 < F; ++f2) in[F + f2] = agg_h[n * F + f2];

    float u[F];
    #pragma unroll
    for (int o = 0; o < F; ++o) u[o] = sbu1[o];
    #pragma unroll
    for (int fi = 0; fi < 2 * F; ++fi) {
        float fv = in[fi];
        #pragma unroll
        for (int o = 0; o < F; ++o) u[o] = fmaf(fv, sWu1[fi * F + o], u[o]);
    }
    #pragma unroll
    for (int o = 0; o < F; ++o) u[o] = siluf(u[o]);

    float u2[F];
    #pragma unroll
    for (int o = 0; o < F; ++o) u2[o] = sbu2[o];
    #pragma unroll
    for (int fi = 0; fi < F; ++fi) {
        float fv = u[fi];
        #pragma unroll
        for (int o = 0; o < F; ++o) u2[o] = fmaf(fv, sWu2[fi * F + o], u2[o]);
    }

    #pragma unroll
    for (int f2 = 0; f2 < F; ++f2) h[n * F + f2] = in[f2] + u2[f2];
    #pragma unroll
    for (int k = 0; k < 3; ++k) x[n * 3 + k] += agg_x[n * 3 + k];
}

__global__ __launch_bounds__(256) void pool_kernel(
    const float* __restrict__ h, const int* __restrict__ batch,
    float* __restrict__ gsum, float* __restrict__ gcnt)
{
    int n = blockIdx.x * blockDim.x + threadIdx.x;
    if (n >= N_NODES) return;
    int g = batch[n];
    #pragma unroll
    for (int f2 = 0; f2 < F; ++f2) unsafeAtomicAdd(&gsum[g * F + f2], h[n * F + f2]);
    unsafeAtomicAdd(&gcnt[g], 1.0f);
}

__global__ void head_kernel(const float* __restrict__ gsum, const float* __restrict__ gcnt,
                            const float* __restrict__ Wp, const float* __restrict__ bp,
                            float* __restrict__ out)
{
    int g = blockIdx.x * blockDim.x + threadIdx.x;
    if (g >= NGRAPH) return;
    float c = fmaxf(gcnt[g], 1.0f);
    float inv = 1.0f / c;
    float acc = bp[0];
    #pragma unroll
    for (int f2 = 0; f2 < F; ++f2) acc = fmaf(gsum[g * F + f2] * inv, Wp[f2], acc);
    out[g] = acc;
}

extern "C" void kernel_launch(void* const* d_in, const int* in_sizes, int n_in,
                              void* d_out, int out_size, void* d_ws, size_t ws_size,
                              hipStream_t stream)
{
    const float* h0    = (const float*)d_in[0];
    const float* pos   = (const float*)d_in[1];
    const int*   eidx  = (const int*)d_in[2];
    const float* eattr = (const float*)d_in[3];
    const int*   batch = (const int*)d_in[4];
    const float* Wm1 = (const float*)d_in[5];
    const float* bm1 = (const float*)d_in[6];
    const float* Wm2 = (const float*)d_in[7];
    const float* bm2 = (const float*)d_in[8];
    const float* Wa  = (const float*)d_in[9];
    const float* ba  = (const float*)d_in[10];
    const float* Wu1 = (const float*)d_in[11];
    const float* bu1 = (const float*)d_in[12];
    const float* Wu2 = (const float*)d_in[13];
    const float* bu2 = (const float*)d_in[14];
    const float* Wx1 = (const float*)d_in[15];
    const float* bx1 = (const float*)d_in[16];
    const float* Wx2 = (const float*)d_in[17];
    const float* bx2 = (const float*)d_in[18];
    const float* Wx3 = (const float*)d_in[19];
    const float* bx3 = (const float*)d_in[20];
    const float* Wp  = (const float*)d_in[21];
    const float* bp  = (const float*)d_in[22];

    float* ws    = (float*)d_ws;
    float* h_cur = ws;                       // N*F
    float* x_cur = h_cur + N_NODES * F;      // N*3
    float* agg_h = x_cur + N_NODES * 3;      // N*F
    float* agg_x = agg_h + N_NODES * F;      // N*3  (contiguous with agg_h)
    float* gsum  = agg_x + N_NODES * 3;      // G*F
    float* gcnt  = gsum + NGRAPH * F;        // G   (contiguous with gsum)

    const int* src = eidx;            // edge_index[0]
    const int* dst = eidx + N_EDGES;  // edge_index[1]

    init_copy<<<512, 256, 0, stream>>>(h0, pos, h_cur, x_cur);

    for (int l = 0; l < NLAYERS; ++l) {
        hipMemsetAsync(agg_h, 0, (size_t)(N_NODES * (F + 3)) * sizeof(float), stream);
        edge_kernel<<<(N_EDGES + 255) / 256, 256, 0, stream>>>(
            h_cur, x_cur, src, dst, eattr,
            Wm1 + l * FEAT * F, bm1 + l * F,
            Wm2 + l * F * F,    bm2 + l * F,
            Wa + l * F,         ba + l,
            Wx1 + l * FEAT * F, bx1 + l * F,
            Wx2 + l * F * F,    bx2 + l * F,
            Wx3 + l * F,        bx3 + l,
            agg_h, agg_x);
        node_kernel<<<(N_NODES + 255) / 256, 256, 0, stream>>>(
            h_cur, x_cur, agg_h, agg_x,
            Wu1 + l * 2 * F * F, bu1 + l * F,
            Wu2 + l * F * F,     bu2 + l * F);
    }

    hipMemsetAsync(gsum, 0, (size_t)(NGRAPH * F + NGRAPH) * sizeof(float), stream);
    pool_kernel<<<(N_NODES + 255) / 256, 256, 0, stream>>>(h_cur, batch, gsum, gcnt);
    head_kernel<<<2, 256, 0, stream>>>(gsum, gcnt, Wp, bp, (float*)d_out);
}

// Round 3
// 875.483 us; speedup vs baseline: 5.4119x; 5.4119x over previous
//
#include <hip/hip_runtime.h>

#define N_NODES 50000
#define N_EDGES 1600000
#define F 11
#define FEAT 27   // 2F + 1 + ED
#define NLAYERS 4
#define NGRAPH 500
#define NVALS 14  // 11 msg_h + 3 msg_x

__device__ __forceinline__ float siluf(float v) { return v * (1.0f / (1.0f + __expf(-v))); }
__device__ __forceinline__ float sigmf(float v) { return 1.0f / (1.0f + __expf(-v)); }

__global__ void init_copy(const float* __restrict__ h0, const float* __restrict__ pos,
                          float* __restrict__ h, float* __restrict__ x) {
    int i = blockIdx.x * blockDim.x + threadIdx.x;
    int stride = gridDim.x * blockDim.x;
    for (int k = i; k < N_NODES * F; k += stride) h[k] = h0[k];
    for (int k = i; k < N_NODES * 3; k += stride) x[k] = pos[k];
}

// ---------- one-time edge sort by dst (counting sort) ----------
__global__ __launch_bounds__(256) void hist_kernel(const int* __restrict__ dst,
                                                   int* __restrict__ deg) {
    int e = blockIdx.x * 256 + threadIdx.x;
    if (e < N_EDGES) atomicAdd(&deg[dst[e]], 1);
}

#define SCAN_T 1024
__global__ __launch_bounds__(SCAN_T) void scan_kernel(const int* __restrict__ deg,
                                                      int* __restrict__ rowptr,
                                                      int* __restrict__ cursor) {
    __shared__ int part[SCAN_T];
    int t = threadIdx.x;
    const int CH = (N_NODES + SCAN_T - 1) / SCAN_T;  // 49
    int base = t * CH;
    int s = 0;
    for (int k = 0; k < CH; ++k) { int idx = base + k; if (idx < N_NODES) s += deg[idx]; }
    part[t] = s;
    __syncthreads();
    for (int off = 1; off < SCAN_T; off <<= 1) {
        int v = (t >= off) ? part[t - off] : 0;
        __syncthreads();
        part[t] += v;
        __syncthreads();
    }
    int run = (t == 0) ? 0 : part[t - 1];
    for (int k = 0; k < CH; ++k) {
        int idx = base + k;
        if (idx < N_NODES) { rowptr[idx] = run; cursor[idx] = run; run += deg[idx]; }
    }
    if (t == SCAN_T - 1) rowptr[N_NODES] = run;
}

__global__ __launch_bounds__(256) void scatter_kernel(
    const int* __restrict__ src, const int* __restrict__ dst,
    const float* __restrict__ eattr, int* __restrict__ cursor,
    int* __restrict__ ssrc, int* __restrict__ sdst, float4* __restrict__ sea) {
    int e = blockIdx.x * 256 + threadIdx.x;
    if (e >= N_EDGES) return;
    int d = dst[e];
    int pos = atomicAdd(&cursor[d], 1);
    ssrc[pos] = src[e];
    sdst[pos] = d;
    sea[pos] = reinterpret_cast<const float4*>(eattr)[e];
}

// ---------- per-layer edge kernel on dst-sorted edges ----------
__global__ __launch_bounds__(256) void edge_kernel(
    const float* __restrict__ h, const float* __restrict__ x,
    const int* __restrict__ ssrc, const int* __restrict__ sdst,
    const float4* __restrict__ sea,
    const float* __restrict__ Wm1, const float* __restrict__ bm1,
    const float* __restrict__ Wm2, const float* __restrict__ bm2,
    const float* __restrict__ Wa,  const float* __restrict__ ba,
    const float* __restrict__ Wx1, const float* __restrict__ bx1,
    const float* __restrict__ Wx2, const float* __restrict__ bx2,
    const float* __restrict__ Wx3, const float* __restrict__ bx3,
    float* __restrict__ agg_h, float* __restrict__ agg_x)
{
    __shared__ float sWm1[FEAT * F], sWm2[F * F], sWx1[FEAT * F], sWx2[F * F];
    __shared__ float sbm1[F], sbm2[F], sWa[F], sbx1[F], sbx2[F], sWx3[F];
    __shared__ float sba, sbx3;
    int t = threadIdx.x;
    for (int i2 = t; i2 < FEAT * F; i2 += 256) { sWm1[i2] = Wm1[i2]; sWx1[i2] = Wx1[i2]; }
    for (int i2 = t; i2 < F * F; i2 += 256)    { sWm2[i2] = Wm2[i2]; sWx2[i2] = Wx2[i2]; }
    if (t < F) {
        sbm1[t] = bm1[t]; sbm2[t] = bm2[t]; sWa[t] = Wa[t];
        sbx1[t] = bx1[t]; sbx2[t] = bx2[t]; sWx3[t] = Wx3[t];
    }
    if (t == 0) { sba = ba[0]; sbx3 = bx3[0]; }
    __syncthreads();

    int e = blockIdx.x * 256 + t;
    if (e >= N_EDGES) return;

    int j = ssrc[e];   // source
    int d = sdst[e];   // target (sorted ascending)

    float feat[FEAT];
    #pragma unroll
    for (int f2 = 0; f2 < F; ++f2) feat[f2] = h[d * F + f2];
    #pragma unroll
    for (int f2 = 0; f2 < F; ++f2) feat[F + f2] = h[j * F + f2];

    float xi0 = x[d * 3 + 0], xi1 = x[d * 3 + 1], xi2 = x[d * 3 + 2];
    float xj0 = x[j * 3 + 0], xj1 = x[j * 3 + 1], xj2 = x[j * 3 + 2];
    float dx = xj0 - xi0, dy = xj1 - xi1, dz = xj2 - xi2;
    float d2 = dx * dx + dy * dy + dz * dz;
    feat[2 * F] = d2;
    float4 ea = sea[e];
    feat[2 * F + 1] = ea.x; feat[2 * F + 2] = ea.y;
    feat[2 * F + 3] = ea.z; feat[2 * F + 4] = ea.w;

    // m = silu(feat @ Wm1 + bm1)
    float m[F];
    #pragma unroll
    for (int o = 0; o < F; ++o) m[o] = sbm1[o];
    #pragma unroll
    for (int fi = 0; fi < FEAT; ++fi) {
        float fv = feat[fi];
        #pragma unroll
        for (int o = 0; o < F; ++o) m[o] = fmaf(fv, sWm1[fi * F + o], m[o]);
    }
    #pragma unroll
    for (int o = 0; o < F; ++o) m[o] = siluf(m[o]);

    // m2 = silu(m @ Wm2 + bm2)
    float m2[F];
    #pragma unroll
    for (int o = 0; o < F; ++o) m2[o] = sbm2[o];
    #pragma unroll
    for (int fi = 0; fi < F; ++fi) {
        float fv = m[fi];
        #pragma unroll
        for (int o = 0; o < F; ++o) m2[o] = fmaf(fv, sWm2[fi * F + o], m2[o]);
    }
    #pragma unroll
    for (int o = 0; o < F; ++o) m2[o] = siluf(m2[o]);

    // attn = sigmoid(m2 @ Wa + ba)
    float attn = sba;
    #pragma unroll
    for (int o = 0; o < F; ++o) attn = fmaf(m2[o], sWa[o], attn);
    attn = sigmf(attn);

    // phi path
    float p1[F];
    #pragma unroll
    for (int o = 0; o < F; ++o) p1[o] = sbx1[o];
    #pragma unroll
    for (int fi = 0; fi < FEAT; ++fi) {
        float fv = feat[fi];
        #pragma unroll
        for (int o = 0; o < F; ++o) p1[o] = fmaf(fv, sWx1[fi * F + o], p1[o]);
    }
    #pragma unroll
    for (int o = 0; o < F; ++o) p1[o] = siluf(p1[o]);

    float p2[F];
    #pragma unroll
    for (int o = 0; o < F; ++o) p2[o] = sbx2[o];
    #pragma unroll
    for (int fi = 0; fi < F; ++fi) {
        float fv = p1[fi];
        #pragma unroll
        for (int o = 0; o < F; ++o) p2[o] = fmaf(fv, sWx2[fi * F + o], p2[o]);
    }
    #pragma unroll
    for (int o = 0; o < F; ++o) p2[o] = siluf(p2[o]);

    float phi = sbx3;
    #pragma unroll
    for (int o = 0; o < F; ++o) phi = fmaf(p2[o], sWx3[o], phi);

    float dist = sqrtf(d2);
    float sc = phi / (dist + 1.0f);

    float vals[NVALS];
    #pragma unroll
    for (int o = 0; o < F; ++o) vals[o] = attn * m2[o];
    vals[F + 0] = (xi0 - xj0) * sc;
    vals[F + 1] = (xi1 - xj1) * sc;
    vals[F + 2] = (xi2 - xj2) * sc;

    // wave-level segmented suffix reduction (keys sorted within wave)
    int lane = t & 63;
    #pragma unroll
    for (int off = 1; off < 64; off <<= 1) {
        int du = __shfl_down(d, off);
        bool ok = (lane + off < 64) && (du == d);
        #pragma unroll
        for (int k = 0; k < NVALS; ++k) {
            float up = __shfl_down(vals[k], off);
            if (ok) vals[k] += up;
        }
    }
    int dprev = __shfl_up(d, 1);
    if (lane == 0 || dprev != d) {
        #pragma unroll
        for (int o = 0; o < F; ++o) unsafeAtomicAdd(&agg_h[d * F + o], vals[o]);
        unsafeAtomicAdd(&agg_x[d * 3 + 0], vals[F + 0]);
        unsafeAtomicAdd(&agg_x[d * 3 + 1], vals[F + 1]);
        unsafeAtomicAdd(&agg_x[d * 3 + 2], vals[F + 2]);
    }
}

__global__ __launch_bounds__(256) void node_kernel(
    float* __restrict__ h, float* __restrict__ x,
    const float* __restrict__ agg_h, const float* __restrict__ agg_x,
    const float* __restrict__ Wu1, const float* __restrict__ bu1,
    const float* __restrict__ Wu2, const float* __restrict__ bu2)
{
    __shared__ float sWu1[2 * F * F], sWu2[F * F], sbu1[F], sbu2[F];
    int t = threadIdx.x;
    for (int i2 = t; i2 < 2 * F * F; i2 += 256) sWu1[i2] = Wu1[i2];
    for (int i2 = t; i2 < F * F; i2 += 256)     sWu2[i2] = Wu2[i2];
    if (t < F) { sbu1[t] = bu1[t]; sbu2[t] = bu2[t]; }
    __syncthreads();

    int n = blockIdx.x * 256 + t;
    if (n >= N_NODES) return;

    float in[2 * F];
    #pragma unroll
    for (int f2 = 0; f2 < F; ++f2) in[f2] = h[n * F + f2];
    #pragma unroll
    for (int f2 = 0; f2 < F; ++f2) in[F + f2] = agg_h[n * F + f2];

    float u[F];
    #pragma unroll
    for (int o = 0; o < F; ++o) u[o] = sbu1[o];
    #pragma unroll
    for (int fi = 0; fi < 2 * F; ++fi) {
        float fv = in[fi];
        #pragma unroll
        for (int o = 0; o < F; ++o) u[o] = fmaf(fv, sWu1[fi * F + o], u[o]);
    }
    #pragma unroll
    for (int o = 0; o < F; ++o) u[o] = siluf(u[o]);

    float u2[F];
    #pragma unroll
    for (int o = 0; o < F; ++o) u2[o] = sbu2[o];
    #pragma unroll
    for (int fi = 0; fi < F; ++fi) {
        float fv = u[fi];
        #pragma unroll
        for (int o = 0; o < F; ++o) u2[o] = fmaf(fv, sWu2[fi * F + o], u2[o]);
    }

    #pragma unroll
    for (int f2 = 0; f2 < F; ++f2) h[n * F + f2] = in[f2] + u2[f2];
    #pragma unroll
    for (int k = 0; k < 3; ++k) x[n * 3 + k] += agg_x[n * 3 + k];
}

// ---------- pool (batch is sorted -> same segmented trick) ----------
__global__ __launch_bounds__(256) void pool_kernel(
    const float* __restrict__ h, const int* __restrict__ batch,
    float* __restrict__ gsum, float* __restrict__ gcnt)
{
    int n = blockIdx.x * blockDim.x + threadIdx.x;
    int lane = threadIdx.x & 63;
    bool valid = (n < N_NODES);
    int g = valid ? batch[n] : -1;
    float vals[F + 1];
    #pragma unroll
    for (int f2 = 0; f2 < F; ++f2) vals[f2] = valid ? h[n * F + f2] : 0.0f;
    vals[F] = valid ? 1.0f : 0.0f;

    #pragma unroll
    for (int off = 1; off < 64; off <<= 1) {
        int gu = __shfl_down(g, off);
        bool ok = (lane + off < 64) && (gu == g);
        #pragma unroll
        for (int k = 0; k < F + 1; ++k) {
            float up = __shfl_down(vals[k], off);
            if (ok) vals[k] += up;
        }
    }
    int gprev = __shfl_up(g, 1);
    if (valid && (lane == 0 || gprev != g)) {
        #pragma unroll
        for (int f2 = 0; f2 < F; ++f2) unsafeAtomicAdd(&gsum[g * F + f2], vals[f2]);
        unsafeAtomicAdd(&gcnt[g], vals[F]);
    }
}

__global__ void head_kernel(const float* __restrict__ gsum, const float* __restrict__ gcnt,
                            const float* __restrict__ Wp, const float* __restrict__ bp,
                            float* __restrict__ out)
{
    int g = blockIdx.x * blockDim.x + threadIdx.x;
    if (g >= NGRAPH) return;
    float c = fmaxf(gcnt[g], 1.0f);
    float inv = 1.0f / c;
    float acc = bp[0];
    #pragma unroll
    for (int f2 = 0; f2 < F; ++f2) acc = fmaf(gsum[g * F + f2] * inv, Wp[f2], acc);
    out[g] = acc;
}

extern "C" void kernel_launch(void* const* d_in, const int* in_sizes, int n_in,
                              void* d_out, int out_size, void* d_ws, size_t ws_size,
                              hipStream_t stream)
{
    const float* h0    = (const float*)d_in[0];
    const float* pos   = (const float*)d_in[1];
    const int*   eidx  = (const int*)d_in[2];
    const float* eattr = (const float*)d_in[3];
    const int*   batch = (const int*)d_in[4];
    const float* Wm1 = (const float*)d_in[5];
    const float* bm1 = (const float*)d_in[6];
    const float* Wm2 = (const float*)d_in[7];
    const float* bm2 = (const float*)d_in[8];
    const float* Wa  = (const float*)d_in[9];
    const float* ba  = (const float*)d_in[10];
    const float* Wu1 = (const float*)d_in[11];
    const float* bu1 = (const float*)d_in[12];
    const float* Wu2 = (const float*)d_in[13];
    const float* bu2 = (const float*)d_in[14];
    const float* Wx1 = (const float*)d_in[15];
    const float* bx1 = (const float*)d_in[16];
    const float* Wx2 = (const float*)d_in[17];
    const float* bx2 = (const float*)d_in[18];
    const float* Wx3 = (const float*)d_in[19];
    const float* bx3 = (const float*)d_in[20];
    const float* Wp  = (const float*)d_in[21];
    const float* bp  = (const float*)d_in[22];

    // workspace layout (float4 array first for alignment)
    char* base = (char*)d_ws;
    float4* sea  = (float4*)base;                         base += (size_t)N_EDGES * 16;
    float* h_cur = (float*)base;                          base += (size_t)N_NODES * F * 4;
    float* x_cur = (float*)base;                          base += (size_t)N_NODES * 3 * 4;
    float* agg_h = (float*)base;                          base += (size_t)N_NODES * F * 4;
    float* agg_x = (float*)base;                          base += (size_t)N_NODES * 3 * 4;
    float* gsum  = (float*)base;                          base += (size_t)NGRAPH * F * 4;
    float* gcnt  = (float*)base;                          base += (size_t)NGRAPH * 4;
    int*   deg   = (int*)base;                            base += (size_t)N_NODES * 4;
    int*   rowptr= (int*)base;                            base += (size_t)(N_NODES + 1) * 4;
    int*   cursor= (int*)base;                            base += (size_t)N_NODES * 4;
    int*   ssrc  = (int*)base;                            base += (size_t)N_EDGES * 4;
    int*   sdst  = (int*)base;                            base += (size_t)N_EDGES * 4;

    const int* src = eidx;            // edge_index[0]
    const int* dst = eidx + N_EDGES;  // edge_index[1]

    // one-time: counting sort of edges by dst
    hipMemsetAsync(deg, 0, (size_t)N_NODES * sizeof(int), stream);
    hist_kernel<<<(N_EDGES + 255) / 256, 256, 0, stream>>>(dst, deg);
    scan_kernel<<<1, SCAN_T, 0, stream>>>(deg, rowptr, cursor);
    scatter_kernel<<<(N_EDGES + 255) / 256, 256, 0, stream>>>(
        src, dst, eattr, cursor, ssrc, sdst, sea);

    init_copy<<<512, 256, 0, stream>>>(h0, pos, h_cur, x_cur);

    for (int l = 0; l < NLAYERS; ++l) {
        hipMemsetAsync(agg_h, 0, (size_t)(N_NODES * (F + 3)) * sizeof(float), stream);
        edge_kernel<<<(N_EDGES + 255) / 256, 256, 0, stream>>>(
            h_cur, x_cur, ssrc, sdst, sea,
            Wm1 + l * FEAT * F, bm1 + l * F,
            Wm2 + l * F * F,    bm2 + l * F,
            Wa + l * F,         ba + l,
            Wx1 + l * FEAT * F, bx1 + l * F,
            Wx2 + l * F * F,    bx2 + l * F,
            Wx3 + l * F,        bx3 + l,
            agg_h, agg_x);
        node_kernel<<<(N_NODES + 255) / 256, 256, 0, stream>>>(
            h_cur, x_cur, agg_h, agg_x,
            Wu1 + l * 2 * F * F, bu1 + l * F,
            Wu2 + l * F * F,     bu2 + l * F);
    }

    hipMemsetAsync(gsum, 0, (size_t)(NGRAPH * F + NGRAPH) * sizeof(float), stream);
    pool_kernel<<<(N_NODES + 255) / 256, 256, 0, stream>>>(h_cur, batch, gsum, gcnt);
    head_kernel<<<2, 256, 0, stream>>>(gsum, gcnt, Wp, bp, (float*)d_out);
}

// Round 4
// 684.089 us; speedup vs baseline: 6.9260x; 1.2798x over previous
//
#include <hip/hip_runtime.h>

#define N_NODES 50000
#define N_EDGES 1600000
#define F 11
#define FEAT 27   // 2F + 1 + ED
#define NLAYERS 4
#define NGRAPH 500
#define NVALS 14       // 11 msg_h + 3 msg_x
#define PRESTRIDE 24   // padded row stride for precomputed tables (96 B, float4-aligned)
#define NBLK 196       // ceil(N_NODES/256)

__device__ __forceinline__ float siluf(float v) { return v * (1.0f / (1.0f + __expf(-v))); }
__device__ __forceinline__ float sigmf(float v) { return 1.0f / (1.0f + __expf(-v)); }

// ---------- one-time edge sort by dst (counting sort) ----------
__global__ __launch_bounds__(256) void hist_kernel(const int* __restrict__ dst,
                                                   int* __restrict__ deg) {
    int e = blockIdx.x * 256 + threadIdx.x;
    if (e < N_EDGES) atomicAdd(&deg[dst[e]], 1);
}

// block-local exclusive scan; emits per-block totals
__global__ __launch_bounds__(256) void scan1_kernel(const int* __restrict__ deg,
                                                    int* __restrict__ part,
                                                    int* __restrict__ bsum) {
    int t = threadIdx.x;
    int i = blockIdx.x * 256 + t;
    int v = (i < N_NODES) ? deg[i] : 0;
    int lane = t & 63, wid = t >> 6;
    int s = v;
    #pragma unroll
    for (int off = 1; off < 64; off <<= 1) {
        int u = __shfl_up(s, off);
        if (lane >= off) s += u;
    }
    __shared__ int wsum[4];
    if (lane == 63) wsum[wid] = s;
    __syncthreads();
    int wpre = 0;
    #pragma unroll
    for (int w = 0; w < 4; ++w) if (w < wid) wpre += wsum[w];
    if (i < N_NODES) part[i] = s + wpre - v;   // exclusive within block
    if (t == 255) bsum[blockIdx.x] = s + wpre; // block total
}

// exclusive scan of the 196 block totals (single small block)
__global__ __launch_bounds__(256) void scan2_kernel(int* __restrict__ bsum) {
    int t = threadIdx.x;
    int v = (t < NBLK) ? bsum[t] : 0;
    int lane = t & 63, wid = t >> 6;
    int s = v;
    #pragma unroll
    for (int off = 1; off < 64; off <<= 1) {
        int u = __shfl_up(s, off);
        if (lane >= off) s += u;
    }
    __shared__ int wsum[4];
    if (lane == 63) wsum[wid] = s;
    __syncthreads();
    int wpre = 0;
    #pragma unroll
    for (int w = 0; w < 4; ++w) if (w < wid) wpre += wsum[w];
    if (t < NBLK) bsum[t] = s + wpre - v;      // exclusive
}

__global__ __launch_bounds__(256) void scan3_kernel(const int* __restrict__ part,
                                                    const int* __restrict__ bsum,
                                                    int* __restrict__ cursor) {
    int i = blockIdx.x * 256 + threadIdx.x;
    if (i < N_NODES) cursor[i] = part[i] + bsum[blockIdx.x];
}

__global__ __launch_bounds__(256) void scatter_kernel(
    const int* __restrict__ src, const int* __restrict__ dst,
    const float* __restrict__ eattr, int* __restrict__ cursor,
    int* __restrict__ ssrc, int* __restrict__ sdst, float4* __restrict__ sea) {
    int e = blockIdx.x * 256 + threadIdx.x;
    if (e >= N_EDGES) return;
    int d = dst[e];
    int pos = atomicAdd(&cursor[d], 1);
    ssrc[pos] = src[e];
    sdst[pos] = d;
    sea[pos] = reinterpret_cast<const float4*>(eattr)[e];
}

// ---------- init: copy state + layer-0 per-node precompute ----------
// preA[n][0:11]  = h@Wm1[0:F]  + bm1   (msg, h_i part, bias folded)
// preA[n][11:22] = h@Wx1[0:F]  + bx1   (phi, h_i part)
// preB[n][0:11]  = h@Wm1[F:2F]         (msg, h_j part)
// preB[n][11:22] = h@Wx1[F:2F]         (phi, h_j part)
__global__ __launch_bounds__(256) void init_kernel(
    const float* __restrict__ h0, const float* __restrict__ pos,
    float* __restrict__ h, float* __restrict__ x,
    const float* __restrict__ Wm1, const float* __restrict__ bm1,
    const float* __restrict__ Wx1, const float* __restrict__ bx1,
    float* __restrict__ preA, float* __restrict__ preB)
{
    __shared__ float sM[2 * F * F], sX[2 * F * F], sbm[F], sbx[F];
    int t = threadIdx.x;
    for (int i2 = t; i2 < 2 * F * F; i2 += 256) { sM[i2] = Wm1[i2]; sX[i2] = Wx1[i2]; }
    if (t < F) { sbm[t] = bm1[t]; sbx[t] = bx1[t]; }
    __syncthreads();

    int n = blockIdx.x * 256 + t;
    if (n >= N_NODES) return;

    float hv[F];
    #pragma unroll
    for (int f2 = 0; f2 < F; ++f2) { hv[f2] = h0[n * F + f2]; h[n * F + f2] = hv[f2]; }
    #pragma unroll
    for (int k = 0; k < 3; ++k) x[n * 3 + k] = pos[n * 3 + k];

    float am[F], bm_[F], ax[F], bx_[F];
    #pragma unroll
    for (int o = 0; o < F; ++o) { am[o] = sbm[o]; ax[o] = sbx[o]; bm_[o] = 0.f; bx_[o] = 0.f; }
    #pragma unroll
    for (int fi = 0; fi < F; ++fi) {
        float v = hv[fi];
        #pragma unroll
        for (int o = 0; o < F; ++o) {
            am[o]  = fmaf(v, sM[fi * F + o], am[o]);
            bm_[o] = fmaf(v, sM[(F + fi) * F + o], bm_[o]);
            ax[o]  = fmaf(v, sX[fi * F + o], ax[o]);
            bx_[o] = fmaf(v, sX[(F + fi) * F + o], bx_[o]);
        }
    }
    #pragma unroll
    for (int o = 0; o < F; ++o) {
        preA[n * PRESTRIDE + o]     = am[o];
        preA[n * PRESTRIDE + F + o] = ax[o];
        preB[n * PRESTRIDE + o]     = bm_[o];
        preB[n * PRESTRIDE + F + o] = bx_[o];
    }
}

// ---------- per-layer edge kernel on dst-sorted edges ----------
__global__ __launch_bounds__(256) void edge_kernel(
    const float* __restrict__ preA, const float* __restrict__ preB,
    const float* __restrict__ x,
    const int* __restrict__ ssrc, const int* __restrict__ sdst,
    const float4* __restrict__ sea,
    const float* __restrict__ Wm1,                                  // rows 22..26 used
    const float* __restrict__ Wm2, const float* __restrict__ bm2,
    const float* __restrict__ Wa,  const float* __restrict__ ba,
    const float* __restrict__ Wx1,                                  // rows 22..26 used
    const float* __restrict__ Wx2, const float* __restrict__ bx2,
    const float* __restrict__ Wx3, const float* __restrict__ bx3,
    float* __restrict__ agg_h, float* __restrict__ agg_x)
{
    __shared__ float sWm2[F * F], sWx2[F * F];
    __shared__ float sMd2[F], sMea[4 * F], sXd2[F], sXea[4 * F];
    __shared__ float sbm2[F], sWa[F], sbx2[F], sWx3[F];
    __shared__ float sba, sbx3;
    int t = threadIdx.x;
    for (int i2 = t; i2 < F * F; i2 += 256) { sWm2[i2] = Wm2[i2]; sWx2[i2] = Wx2[i2]; }
    if (t < F) {
        sMd2[t] = Wm1[22 * F + t]; sXd2[t] = Wx1[22 * F + t];
        sbm2[t] = bm2[t]; sWa[t] = Wa[t]; sbx2[t] = bx2[t]; sWx3[t] = Wx3[t];
    }
    if (t >= 64 && t < 64 + 4 * F) { int k = t - 64; sMea[k] = Wm1[23 * F + k]; sXea[k] = Wx1[23 * F + k]; }
    if (t == 0) { sba = ba[0]; sbx3 = bx3[0]; }
    __syncthreads();

    int e = blockIdx.x * 256 + t;
    if (e >= N_EDGES) return;

    int j = ssrc[e];   // source
    int d = sdst[e];   // target (sorted ascending)

    // gather precomputed per-node partials (aligned 96B rows)
    float pav[22], pbv[22];
    {
        const float4* pa4 = reinterpret_cast<const float4*>(preA + (size_t)d * PRESTRIDE);
        const float4* pb4 = reinterpret_cast<const float4*>(preB + (size_t)j * PRESTRIDE);
        #pragma unroll
        for (int q = 0; q < 5; ++q) {
            float4 va = pa4[q], vb = pb4[q];
            pav[4 * q + 0] = va.x; pav[4 * q + 1] = va.y; pav[4 * q + 2] = va.z; pav[4 * q + 3] = va.w;
            pbv[4 * q + 0] = vb.x; pbv[4 * q + 1] = vb.y; pbv[4 * q + 2] = vb.z; pbv[4 * q + 3] = vb.w;
        }
        float2 ta = *reinterpret_cast<const float2*>(preA + (size_t)d * PRESTRIDE + 20);
        float2 tb = *reinterpret_cast<const float2*>(preB + (size_t)j * PRESTRIDE + 20);
        pav[20] = ta.x; pav[21] = ta.y; pbv[20] = tb.x; pbv[21] = tb.y;
    }

    float xi0 = x[d * 3 + 0], xi1 = x[d * 3 + 1], xi2 = x[d * 3 + 2];
    float xj0 = x[j * 3 + 0], xj1 = x[j * 3 + 1], xj2 = x[j * 3 + 2];
    float dx = xj0 - xi0, dy = xj1 - xi1, dz = xj2 - xi2;
    float d2 = dx * dx + dy * dy + dz * dz;
    float4 ea = sea[e];

    // layer-1 of both MLPs: precomputed node parts + edge-specific terms
    float tm[F], tx[F];
    #pragma unroll
    for (int o = 0; o < F; ++o) {
        tm[o] = pav[o] + pbv[o];
        tx[o] = pav[F + o] + pbv[F + o];
    }
    #pragma unroll
    for (int o = 0; o < F; ++o) {
        tm[o] = fmaf(d2, sMd2[o], tm[o]);
        tx[o] = fmaf(d2, sXd2[o], tx[o]);
    }
    float eav[4] = {ea.x, ea.y, ea.z, ea.w};
    #pragma unroll
    for (int k = 0; k < 4; ++k) {
        float v = eav[k];
        #pragma unroll
        for (int o = 0; o < F; ++o) {
            tm[o] = fmaf(v, sMea[k * F + o], tm[o]);
            tx[o] = fmaf(v, sXea[k * F + o], tx[o]);
        }
    }
    #pragma unroll
    for (int o = 0; o < F; ++o) { tm[o] = siluf(tm[o]); tx[o] = siluf(tx[o]); }

    // layer-2
    float m2[F], p2[F];
    #pragma unroll
    for (int o = 0; o < F; ++o) { m2[o] = sbm2[o]; p2[o] = sbx2[o]; }
    #pragma unroll
    for (int fi = 0; fi < F; ++fi) {
        float a = tm[fi], b = tx[fi];
        #pragma unroll
        for (int o = 0; o < F; ++o) {
            m2[o] = fmaf(a, sWm2[fi * F + o], m2[o]);
            p2[o] = fmaf(b, sWx2[fi * F + o], p2[o]);
        }
    }
    #pragma unroll
    for (int o = 0; o < F; ++o) { m2[o] = siluf(m2[o]); p2[o] = siluf(p2[o]); }

    // heads
    float attn = sba, phi = sbx3;
    #pragma unroll
    for (int o = 0; o < F; ++o) {
        attn = fmaf(m2[o], sWa[o], attn);
        phi  = fmaf(p2[o], sWx3[o], phi);
    }
    attn = sigmf(attn);

    float dist = sqrtf(d2);
    float sc = phi / (dist + 1.0f);

    float vals[NVALS];
    #pragma unroll
    for (int o = 0; o < F; ++o) vals[o] = attn * m2[o];
    vals[F + 0] = (xi0 - xj0) * sc;
    vals[F + 1] = (xi1 - xj1) * sc;
    vals[F + 2] = (xi2 - xj2) * sc;

    // wave-level segmented suffix reduction (keys sorted within wave)
    int lane = t & 63;
    #pragma unroll
    for (int off = 1; off < 64; off <<= 1) {
        int du = __shfl_down(d, off);
        bool ok = (lane + off < 64) && (du == d);
        #pragma unroll
        for (int k = 0; k < NVALS; ++k) {
            float up = __shfl_down(vals[k], off);
            if (ok) vals[k] += up;
        }
    }
    int dprev = __shfl_up(d, 1);
    if (lane == 0 || dprev != d) {
        #pragma unroll
        for (int o = 0; o < F; ++o) unsafeAtomicAdd(&agg_h[d * F + o], vals[o]);
        unsafeAtomicAdd(&agg_x[d * 3 + 0], vals[F + 0]);
        unsafeAtomicAdd(&agg_x[d * 3 + 1], vals[F + 1]);
        unsafeAtomicAdd(&agg_x[d * 3 + 2], vals[F + 2]);
    }
}

// ---------- node update + fused precompute for next layer ----------
__global__ __launch_bounds__(256) void node_kernel(
    float* __restrict__ h, float* __restrict__ x,
    const float* __restrict__ agg_h, const float* __restrict__ agg_x,
    const float* __restrict__ Wu1, const float* __restrict__ bu1,
    const float* __restrict__ Wu2, const float* __restrict__ bu2,
    const float* __restrict__ Wm1n, const float* __restrict__ bm1n,
    const float* __restrict__ Wx1n, const float* __restrict__ bx1n,
    float* __restrict__ preA, float* __restrict__ preB, int has_next)
{
    __shared__ float sWu1[2 * F * F], sWu2[F * F], sbu1[F], sbu2[F];
    __shared__ float sM[2 * F * F], sX[2 * F * F], sbm[F], sbx[F];
    int t = threadIdx.x;
    for (int i2 = t; i2 < 2 * F * F; i2 += 256) sWu1[i2] = Wu1[i2];
    for (int i2 = t; i2 < F * F; i2 += 256)     sWu2[i2] = Wu2[i2];
    if (t < F) { sbu1[t] = bu1[t]; sbu2[t] = bu2[t]; }
    if (has_next) {
        for (int i2 = t; i2 < 2 * F * F; i2 += 256) { sM[i2] = Wm1n[i2]; sX[i2] = Wx1n[i2]; }
        if (t < F) { sbm[t] = bm1n[t]; sbx[t] = bx1n[t]; }
    }
    __syncthreads();

    int n = blockIdx.x * 256 + t;
    if (n >= N_NODES) return;

    float in[2 * F];
    #pragma unroll
    for (int f2 = 0; f2 < F; ++f2) in[f2] = h[n * F + f2];
    #pragma unroll
    for (int f2 = 0; f2 < F; ++f2) in[F + f2] = agg_h[n * F + f2];

    float u[F];
    #pragma unroll
    for (int o = 0; o < F; ++o) u[o] = sbu1[o];
    #pragma unroll
    for (int fi = 0; fi < 2 * F; ++fi) {
        float fv = in[fi];
        #pragma unroll
        for (int o = 0; o < F; ++o) u[o] = fmaf(fv, sWu1[fi * F + o], u[o]);
    }
    #pragma unroll
    for (int o = 0; o < F; ++o) u[o] = siluf(u[o]);

    float hn[F];
    #pragma unroll
    for (int o = 0; o < F; ++o) hn[o] = in[o] + sbu2[o];
    #pragma unroll
    for (int fi = 0; fi < F; ++fi) {
        float fv = u[fi];
        #pragma unroll
        for (int o = 0; o < F; ++o) hn[o] = fmaf(fv, sWu2[fi * F + o], hn[o]);
    }

    #pragma unroll
    for (int f2 = 0; f2 < F; ++f2) h[n * F + f2] = hn[f2];
    #pragma unroll
    for (int k = 0; k < 3; ++k) x[n * 3 + k] += agg_x[n * 3 + k];

    if (has_next) {
        float am[F], bm_[F], ax[F], bx_[F];
        #pragma unroll
        for (int o = 0; o < F; ++o) { am[o] = sbm[o]; ax[o] = sbx[o]; bm_[o] = 0.f; bx_[o] = 0.f; }
        #pragma unroll
        for (int fi = 0; fi < F; ++fi) {
            float v = hn[fi];
            #pragma unroll
            for (int o = 0; o < F; ++o) {
                am[o]  = fmaf(v, sM[fi * F + o], am[o]);
                bm_[o] = fmaf(v, sM[(F + fi) * F + o], bm_[o]);
                ax[o]  = fmaf(v, sX[fi * F + o], ax[o]);
                bx_[o] = fmaf(v, sX[(F + fi) * F + o], bx_[o]);
            }
        }
        #pragma unroll
        for (int o = 0; o < F; ++o) {
            preA[n * PRESTRIDE + o]     = am[o];
            preA[n * PRESTRIDE + F + o] = ax[o];
            preB[n * PRESTRIDE + o]     = bm_[o];
            preB[n * PRESTRIDE + F + o] = bx_[o];
        }
    }
}

// ---------- pool (batch is sorted -> same segmented trick) ----------
__global__ __launch_bounds__(256) void pool_kernel(
    const float* __restrict__ h, const int* __restrict__ batch,
    float* __restrict__ gsum, float* __restrict__ gcnt)
{
    int n = blockIdx.x * blockDim.x + threadIdx.x;
    int lane = threadIdx.x & 63;
    bool valid = (n < N_NODES);
    int g = valid ? batch[n] : -1;
    float vals[F + 1];
    #pragma unroll
    for (int f2 = 0; f2 < F; ++f2) vals[f2] = valid ? h[n * F + f2] : 0.0f;
    vals[F] = valid ? 1.0f : 0.0f;

    #pragma unroll
    for (int off = 1; off < 64; off <<= 1) {
        int gu = __shfl_down(g, off);
        bool ok = (lane + off < 64) && (gu == g);
        #pragma unroll
        for (int k = 0; k < F + 1; ++k) {
            float up = __shfl_down(vals[k], off);
            if (ok) vals[k] += up;
        }
    }
    int gprev = __shfl_up(g, 1);
    if (valid && (lane == 0 || gprev != g)) {
        #pragma unroll
        for (int f2 = 0; f2 < F; ++f2) unsafeAtomicAdd(&gsum[g * F + f2], vals[f2]);
        unsafeAtomicAdd(&gcnt[g], vals[F]);
    }
}

__global__ void head_kernel(const float* __restrict__ gsum, const float* __restrict__ gcnt,
                            const float* __restrict__ Wp, const float* __restrict__ bp,
                            float* __restrict__ out)
{
    int g = blockIdx.x * blockDim.x + threadIdx.x;
    if (g >= NGRAPH) return;
    float c = fmaxf(gcnt[g], 1.0f);
    float inv = 1.0f / c;
    float acc = bp[0];
    #pragma unroll
    for (int f2 = 0; f2 < F; ++f2) acc = fmaf(gsum[g * F + f2] * inv, Wp[f2], acc);
    out[g] = acc;
}

extern "C" void kernel_launch(void* const* d_in, const int* in_sizes, int n_in,
                              void* d_out, int out_size, void* d_ws, size_t ws_size,
                              hipStream_t stream)
{
    const float* h0    = (const float*)d_in[0];
    const float* pos   = (const float*)d_in[1];
    const int*   eidx  = (const int*)d_in[2];
    const float* eattr = (const float*)d_in[3];
    const int*   batch = (const int*)d_in[4];
    const float* Wm1 = (const float*)d_in[5];
    const float* bm1 = (const float*)d_in[6];
    const float* Wm2 = (const float*)d_in[7];
    const float* bm2 = (const float*)d_in[8];
    const float* Wa  = (const float*)d_in[9];
    const float* ba  = (const float*)d_in[10];
    const float* Wu1 = (const float*)d_in[11];
    const float* bu1 = (const float*)d_in[12];
    const float* Wu2 = (const float*)d_in[13];
    const float* bu2 = (const float*)d_in[14];
    const float* Wx1 = (const float*)d_in[15];
    const float* bx1 = (const float*)d_in[16];
    const float* Wx2 = (const float*)d_in[17];
    const float* bx2 = (const float*)d_in[18];
    const float* Wx3 = (const float*)d_in[19];
    const float* bx3 = (const float*)d_in[20];
    const float* Wp  = (const float*)d_in[21];
    const float* bp  = (const float*)d_in[22];

    // workspace layout (16B-aligned chunks first)
    char* base = (char*)d_ws;
    float4* sea  = (float4*)base;                         base += (size_t)N_EDGES * 16;
    float* preA  = (float*)base;                          base += (size_t)N_NODES * PRESTRIDE * 4;
    float* preB  = (float*)base;                          base += (size_t)N_NODES * PRESTRIDE * 4;
    float* h_cur = (float*)base;                          base += (size_t)N_NODES * F * 4;
    float* x_cur = (float*)base;                          base += (size_t)N_NODES * 3 * 4;
    float* agg_h = (float*)base;                          base += (size_t)N_NODES * F * 4;
    float* agg_x = (float*)base;                          base += (size_t)N_NODES * 3 * 4;
    float* gsum  = (float*)base;                          base += (size_t)NGRAPH * F * 4;
    float* gcnt  = (float*)base;                          base += (size_t)NGRAPH * 4;
    int*   deg   = (int*)base;                            base += (size_t)N_NODES * 4;
    int*   part  = (int*)base;                            base += (size_t)N_NODES * 4;
    int*   bsum  = (int*)base;                            base += (size_t)256 * 4;
    int*   cursor= (int*)base;                            base += (size_t)N_NODES * 4;
    int*   ssrc  = (int*)base;                            base += (size_t)N_EDGES * 4;
    int*   sdst  = (int*)base;                            base += (size_t)N_EDGES * 4;

    const int* src = eidx;            // edge_index[0]
    const int* dst = eidx + N_EDGES;  // edge_index[1]

    // one-time: counting sort of edges by dst (fast multi-block scan)
    hipMemsetAsync(deg, 0, (size_t)N_NODES * sizeof(int), stream);
    hist_kernel<<<(N_EDGES + 255) / 256, 256, 0, stream>>>(dst, deg);
    scan1_kernel<<<NBLK, 256, 0, stream>>>(deg, part, bsum);
    scan2_kernel<<<1, 256, 0, stream>>>(bsum);
    scan3_kernel<<<NBLK, 256, 0, stream>>>(part, bsum, cursor);
    scatter_kernel<<<(N_EDGES + 255) / 256, 256, 0, stream>>>(
        src, dst, eattr, cursor, ssrc, sdst, sea);

    // init state + layer-0 precompute
    init_kernel<<<NBLK, 256, 0, stream>>>(h0, pos, h_cur, x_cur,
                                          Wm1, bm1, Wx1, bx1, preA, preB);

    for (int l = 0; l < NLAYERS; ++l) {
        hipMemsetAsync(agg_h, 0, (size_t)(N_NODES * (F + 3)) * sizeof(float), stream);
        edge_kernel<<<(N_EDGES + 255) / 256, 256, 0, stream>>>(
            preA, preB, x_cur, ssrc, sdst, sea,
            Wm1 + l * FEAT * F,
            Wm2 + l * F * F,    bm2 + l * F,
            Wa + l * F,         ba + l,
            Wx1 + l * FEAT * F,
            Wx2 + l * F * F,    bx2 + l * F,
            Wx3 + l * F,        bx3 + l,
            agg_h, agg_x);
        int nl = l + 1;
        int has_next = (nl < NLAYERS) ? 1 : 0;
        int wl = has_next ? nl : l;  // harmless valid pointers when !has_next
        node_kernel<<<NBLK, 256, 0, stream>>>(
            h_cur, x_cur, agg_h, agg_x,
            Wu1 + l * 2 * F * F, bu1 + l * F,
            Wu2 + l * F * F,     bu2 + l * F,
            Wm1 + wl * FEAT * F, bm1 + wl * F,
            Wx1 + wl * FEAT * F, bx1 + wl * F,
            preA, preB, has_next);
    }

    hipMemsetAsync(gsum, 0, (size_t)(NGRAPH * F + NGRAPH) * sizeof(float), stream);
    pool_kernel<<<(N_NODES + 255) / 256, 256, 0, stream>>>(h_cur, batch, gsum, gcnt);
    head_kernel<<<2, 256, 0, stream>>>(gsum, gcnt, Wp, bp, (float*)d_out);
}